// Round 7
// baseline (407.204 us; speedup 1.0000x reference)
//
#include <hip/hip_runtime.h>
#include <cstdint>

// TCNN hash-grid fwd, R7 (= R6 + 2 points/thread for MLP/ILP):
//  - bf16-packed tables in ws (convert pre-pass)
//  - hash levels 3-7 in ONE launch (slice = blockIdx>>12), 2 points/thread,
//    writing compact bf16x2 planes (ws)
//  - merge kernel: dense 0-1 from LDS, level 2 from L2 (x-paired), 5 plane
//    reads, full 64 B row NT writes; 2 points/thread.

constexpr int      kBatch  = 2097152;
constexpr int      kHalf   = kBatch / 2;
constexpr uint32_t kHash   = 1u << 19;
constexpr size_t   kWsNeed = (size_t)(16 + 40) * 1024 * 1024;

typedef float    f32x2 __attribute__((ext_vector_type(2)));
typedef float    f32x4 __attribute__((ext_vector_type(4)));
typedef uint32_t u32x2 __attribute__((ext_vector_type(2)));

constexpr uint32_t kL0Ents = 16u + 16u * 16u + 16u * 16u * 16u + 1u;   // 4369
constexpr uint32_t kL1Ents = 32u + 32u * 32u + 32u * 32u * 32u + 1u;   // 33825

__device__ __forceinline__ uint32_t bf16rn(float f) {
    uint32_t u = __float_as_uint(f);
    return (u + 0x7FFFu + ((u >> 16) & 1u)) >> 16;
}
__device__ __forceinline__ float bf_lo(uint32_t w) {
    return __uint_as_float(w << 16);
}
__device__ __forceinline__ float bf_hi(uint32_t w) {
    return __uint_as_float(w & 0xFFFF0000u);
}

// ---- pack f32 table [8,2^19,2] -> bf16x2 words [8,2^19] ----
__global__ __launch_bounds__(256) void convert_tables(
    const float* __restrict__ table, uint32_t* __restrict__ bt)
{
    const size_t i = (size_t)blockIdx.x * 256 + threadIdx.x;
    const f32x4 v = __builtin_nontemporal_load(
        reinterpret_cast<const f32x4*>(table) + i);
    u32x2 o;
    o.x = bf16rn(v.x) | (bf16rn(v.y) << 16);
    o.y = bf16rn(v.z) | (bf16rn(v.w) << 16);
    __builtin_nontemporal_store(o, reinterpret_cast<u32x2*>(bt) + i);
}

// ---- hash levels 3..7, single launch, 2 pts/thread, bf16x2 plane out ----
__global__ __launch_bounds__(256) void hash_levels(
    const float* __restrict__ xs,
    const uint32_t* __restrict__ bt,
    uint32_t* __restrict__ planes)     // 5 x kBatch u32
{
    const uint32_t lvl = blockIdx.x >> 12;               // 0..4 -> level 3..7
    const int base = (int)(blockIdx.x & 4095u) * 256 + threadIdx.x;
    const uint32_t* __restrict__ tl = bt + (size_t)(lvl + 3u) * kHash;
    const float scale = (float)((128u << lvl) - 1u);

#pragma unroll
    for (int it = 0; it < 2; ++it) {
        const int p = base + it * kHalf;

        const float px = xs[3 * p + 0];
        const float py = xs[3 * p + 1];
        const float pz = xs[3 * p + 2];

        const float fx = px * scale + 0.5f;
        const float fy = py * scale + 0.5f;
        const float fz = pz * scale + 0.5f;
        const float flx = floorf(fx), fly = floorf(fy), flz = floorf(fz);
        const float rx = fx - flx, ry = fy - fly, rz = fz - flz;
        const uint32_t bx = (uint32_t)flx;
        const uint32_t by = (uint32_t)fly;
        const uint32_t bz = (uint32_t)flz;

        const uint32_t hy0 = by * 2654435761u, hy1 = (by + 1u) * 2654435761u;
        const uint32_t hz0 = bz * 805459861u,  hz1 = (bz + 1u) * 805459861u;
        uint32_t hyz[4] = {hy0 ^ hz0, hy1 ^ hz0, hy0 ^ hz1, hy1 ^ hz1};

        uint32_t i0[4];
#pragma unroll
        for (int k = 0; k < 4; ++k) i0[k] = (bx ^ hyz[k]) & (kHash - 1u);

        u32x2 v[4];
#pragma unroll
        for (int k = 0; k < 4; ++k)
            v[k] = *reinterpret_cast<const u32x2*>(tl + (i0[k] & ~1u));

        const bool bxodd = (bx & 1u) != 0u;
        uint32_t e0[4], e1[4];
        if (bxodd) {
#pragma unroll
            for (int k = 0; k < 4; ++k)
                e1[k] = tl[((bx + 1u) ^ hyz[k]) & (kHash - 1u)];
        }
#pragma unroll
        for (int k = 0; k < 4; ++k) {
            const bool lo = (i0[k] & 1u) != 0u;
            e0[k] = lo ? v[k].y : v[k].x;
            if (!bxodd) e1[k] = lo ? v[k].x : v[k].y;
        }

        const float wx0 = 1.0f - rx, wx1 = rx;
        const float wyz[4] = {(1.0f - ry) * (1.0f - rz), ry * (1.0f - rz),
                              (1.0f - ry) * rz,          ry * rz};
        float a0 = 0.0f, a1 = 0.0f;
#pragma unroll
        for (int k = 0; k < 4; ++k) {
            const float w0 = wx0 * wyz[k], w1 = wx1 * wyz[k];
            a0 = fmaf(bf_lo(e0[k]), w0, fmaf(bf_lo(e1[k]), w1, a0));
            a1 = fmaf(bf_hi(e0[k]), w0, fmaf(bf_hi(e1[k]), w1, a1));
        }

        planes[(size_t)lvl * kBatch + p] = bf16rn(a0) | (bf16rn(a1) << 16);
    }
}

// ---- merge: dense 0-1 (LDS), 2 (global paired), + 5 planes -> full rows ----
__global__ __launch_bounds__(1024) void merge_dense(
    const float* __restrict__ xs,
    const uint32_t* __restrict__ bt,
    const uint32_t* __restrict__ planes,
    float* __restrict__ out)
{
    __shared__ uint32_t sh[kL0Ents + kL1Ents];  // 152.8 KB

    for (uint32_t i = threadIdx.x; i < kL0Ents; i += 1024u)
        sh[i] = bt[i];
    for (uint32_t i = threadIdx.x; i < kL1Ents; i += 1024u)
        sh[kL0Ents + i] = bt[kHash + i];
    __syncthreads();

    const int base = blockIdx.x * 1024 + threadIdx.x;

#pragma unroll
    for (int it = 0; it < 2; ++it) {
        const int p = base + it * kHalf;
        const float px = xs[3 * p + 0];
        const float py = xs[3 * p + 1];
        const float pz = xs[3 * p + 2];

        float row[16];

        // levels 0,1 from LDS
#pragma unroll
        for (int l = 0; l < 2; ++l) {
            const uint32_t res    = (l == 0) ? 16u : 32u;
            const uint32_t shbase = (l == 0) ? 0u  : kL0Ents;
            const float scale = (float)(res - 1u);
            const float fx = px * scale + 0.5f;
            const float fy = py * scale + 0.5f;
            const float fz = pz * scale + 0.5f;
            const float flx = floorf(fx), fly = floorf(fy), flz = floorf(fz);
            const float rx = fx - flx, ry = fy - fly, rz = fz - flz;
            const uint32_t bx = (uint32_t)flx;
            const uint32_t by = (uint32_t)fly;
            const uint32_t bz = (uint32_t)flz;

            const float wx0 = 1.0f - rx, wx1 = rx;
            const float wyz[4] = {(1.0f - ry) * (1.0f - rz), ry * (1.0f - rz),
                                  (1.0f - ry) * rz,          ry * rz};
            float a0 = 0.0f, a1 = 0.0f;
#pragma unroll
            for (int k = 0; k < 4; ++k) {
                const uint32_t oy = k & 1u, oz = (k >> 1) & 1u;
                const uint32_t i0 = bx + (by + oy) * res + (bz + oz) * res * res;
                const uint32_t eA = sh[shbase + i0];
                const uint32_t eB = sh[shbase + i0 + 1u];
                const float w0 = wx0 * wyz[k], w1 = wx1 * wyz[k];
                a0 = fmaf(bf_lo(eA), w0, fmaf(bf_lo(eB), w1, a0));
                a1 = fmaf(bf_hi(eA), w0, fmaf(bf_hi(eB), w1, a1));
            }
            row[2 * l + 0] = a0;
            row[2 * l + 1] = a1;
        }

        // level 2 (res 64) from global, x-paired
        {
            const uint32_t res = 64u;
            const uint32_t* __restrict__ tl = bt + (size_t)2 * kHash;
            const float scale = (float)(res - 1u);
            const float fx = px * scale + 0.5f;
            const float fy = py * scale + 0.5f;
            const float fz = pz * scale + 0.5f;
            const float flx = floorf(fx), fly = floorf(fy), flz = floorf(fz);
            const float rx = fx - flx, ry = fy - fly, rz = fz - flz;
            const uint32_t bx = (uint32_t)flx;
            const uint32_t by = (uint32_t)fly;
            const uint32_t bz = (uint32_t)flz;

            uint32_t i0[4];
#pragma unroll
            for (int k = 0; k < 4; ++k) {
                const uint32_t oy = k & 1u, oz = (k >> 1) & 1u;
                i0[k] = bx + (by + oy) * res + (bz + oz) * res * res;
            }
            u32x2 v[4];
#pragma unroll
            for (int k = 0; k < 4; ++k)
                v[k] = *reinterpret_cast<const u32x2*>(tl + (i0[k] & ~1u));

            const bool bxodd = (bx & 1u) != 0u;
            uint32_t e0[4], e1[4];
            if (bxodd) {
#pragma unroll
                for (int k = 0; k < 4; ++k) e1[k] = tl[i0[k] + 1u];
            }
#pragma unroll
            for (int k = 0; k < 4; ++k) {
                e0[k] = bxodd ? v[k].y : v[k].x;
                if (!bxodd) e1[k] = v[k].y;
            }

            const float wx0 = 1.0f - rx, wx1 = rx;
            const float wyz[4] = {(1.0f - ry) * (1.0f - rz), ry * (1.0f - rz),
                                  (1.0f - ry) * rz,          ry * rz};
            float a0 = 0.0f, a1 = 0.0f;
#pragma unroll
            for (int k = 0; k < 4; ++k) {
                const float w0 = wx0 * wyz[k], w1 = wx1 * wyz[k];
                a0 = fmaf(bf_lo(e0[k]), w0, fmaf(bf_lo(e1[k]), w1, a0));
                a1 = fmaf(bf_hi(e0[k]), w0, fmaf(bf_hi(e1[k]), w1, a1));
            }
            row[4] = a0;
            row[5] = a1;
        }

        // hash levels from planes
#pragma unroll
        for (int l = 0; l < 5; ++l) {
            const uint32_t w = planes[(size_t)l * kBatch + p];
            row[6 + 2 * l + 0] = bf_lo(w);
            row[6 + 2 * l + 1] = bf_hi(w);
        }

        f32x4* op = reinterpret_cast<f32x4*>(out + (size_t)p * 16u);
#pragma unroll
        for (int i = 0; i < 4; ++i) {
            f32x4 q;
            q.x = row[4 * i + 0]; q.y = row[4 * i + 1];
            q.z = row[4 * i + 2]; q.w = row[4 * i + 3];
            __builtin_nontemporal_store(q, op + i);
        }
    }
}

// ---- fallback (small ws): monolithic f32 kernel (R1) ----
__global__ __launch_bounds__(256) void tcnn_grid_fallback(
    const float* __restrict__ xs, const float* __restrict__ table,
    float* __restrict__ out)
{
    const int p = blockIdx.x * 256 + threadIdx.x;
    const float px = xs[3 * p + 0], py = xs[3 * p + 1], pz = xs[3 * p + 2];
    float o[16];
#pragma unroll
    for (int l = 0; l < 8; ++l) {
        const uint32_t res = 16u << l;
        const bool dense = (l < 3);
        const float scale = (float)(res - 1u);
        const float fx = px * scale + 0.5f, fy = py * scale + 0.5f,
                    fz = pz * scale + 0.5f;
        const float flx = floorf(fx), fly = floorf(fy), flz = floorf(fz);
        const float rx = fx - flx, ry = fy - fly, rz = fz - flz;
        const uint32_t bx = (uint32_t)flx, by = (uint32_t)fly,
                       bz = (uint32_t)flz;
        const float* tl = table + (size_t)l * kHash * 2u;
        float a0 = 0.0f, a1 = 0.0f;
#pragma unroll
        for (int c = 0; c < 8; ++c) {
            const uint32_t ox = c & 1u, oy = (c >> 1) & 1u, oz = (c >> 2) & 1u;
            uint32_t idx;
            if (dense)
                idx = (bx + ox) + (by + oy) * res + (bz + oz) * res * res;
            else
                idx = ((bx + ox) ^ ((by + oy) * 2654435761u) ^
                       ((bz + oz) * 805459861u)) & (kHash - 1u);
            const float2 f = *reinterpret_cast<const float2*>(tl + 2u * (size_t)idx);
            const float w = (ox ? rx : 1.0f - rx) * (oy ? ry : 1.0f - ry) *
                            (oz ? rz : 1.0f - rz);
            a0 = fmaf(f.x, w, a0);
            a1 = fmaf(f.y, w, a1);
        }
        o[2 * l] = a0; o[2 * l + 1] = a1;
    }
    float4* op = reinterpret_cast<float4*>(out + (size_t)p * 16u);
#pragma unroll
    for (int i = 0; i < 4; ++i)
        op[i] = make_float4(o[4 * i], o[4 * i + 1], o[4 * i + 2], o[4 * i + 3]);
}

extern "C" void kernel_launch(void* const* d_in, const int* in_sizes, int n_in,
                              void* d_out, int out_size, void* d_ws,
                              size_t ws_size, hipStream_t stream) {
    const float* xs    = (const float*)d_in[0];
    const float* table = (const float*)d_in[1];
    float*       out   = (float*)d_out;

    if (ws_size < kWsNeed) {
        hipLaunchKernelGGL(tcnn_grid_fallback, dim3(kBatch / 256), dim3(256),
                           0, stream, xs, table, out);
        return;
    }

    uint32_t* bt     = (uint32_t*)d_ws;                 // 16 MB bf16x2 tables
    uint32_t* planes = bt + (size_t)8 * kHash;          // 5 x 8 MB bf16x2

    hipLaunchKernelGGL(convert_tables, dim3(kBatch / 256), dim3(256), 0,
                       stream, table, bt);

    hipLaunchKernelGGL(hash_levels, dim3(5 * (kHalf / 256)), dim3(256), 0,
                       stream, xs, bt, planes);

    hipLaunchKernelGGL(merge_dense, dim3(kHalf / 1024), dim3(1024), 0,
                       stream, xs, bt, planes, out);
}

// Round 8
// 393.098 us; speedup vs baseline: 1.0359x; 1.0359x over previous
//
#include <hip/hip_runtime.h>
#include <cstdint>

// TCNN hash-grid fwd, R8 (= R6 + persistent merge blocks):
//  - bf16-packed tables in ws (convert pre-pass)
//  - hash levels 3-7 in ONE launch (slice = blockIdx>>13), 1 pt/thread,
//    writing compact bf16x2 planes (ws)   [R6 form — R7's 2pt regressed]
//  - merge: 256 persistent blocks (1/CU), LDS staged ONCE per block,
//    grid-stride over points; dense 0-1 from LDS, 2 from L2 (x-paired),
//    5 plane reads, full 64 B row NT writes.

constexpr int      kBatch  = 2097152;
constexpr uint32_t kHash   = 1u << 19;
constexpr size_t   kWsNeed = (size_t)(16 + 40) * 1024 * 1024;

typedef float    f32x2 __attribute__((ext_vector_type(2)));
typedef float    f32x4 __attribute__((ext_vector_type(4)));
typedef uint32_t u32x2 __attribute__((ext_vector_type(2)));

constexpr uint32_t kL0Ents = 16u + 16u * 16u + 16u * 16u * 16u + 1u;   // 4369
constexpr uint32_t kL1Ents = 32u + 32u * 32u + 32u * 32u * 32u + 1u;   // 33825

__device__ __forceinline__ uint32_t bf16rn(float f) {
    uint32_t u = __float_as_uint(f);
    return (u + 0x7FFFu + ((u >> 16) & 1u)) >> 16;
}
__device__ __forceinline__ float bf_lo(uint32_t w) {
    return __uint_as_float(w << 16);
}
__device__ __forceinline__ float bf_hi(uint32_t w) {
    return __uint_as_float(w & 0xFFFF0000u);
}

// ---- pack f32 table [8,2^19,2] -> bf16x2 words [8,2^19] ----
__global__ __launch_bounds__(256) void convert_tables(
    const float* __restrict__ table, uint32_t* __restrict__ bt)
{
    const size_t i = (size_t)blockIdx.x * 256 + threadIdx.x;
    const f32x4 v = __builtin_nontemporal_load(
        reinterpret_cast<const f32x4*>(table) + i);
    u32x2 o;
    o.x = bf16rn(v.x) | (bf16rn(v.y) << 16);
    o.y = bf16rn(v.z) | (bf16rn(v.w) << 16);
    __builtin_nontemporal_store(o, reinterpret_cast<u32x2*>(bt) + i);
}

// ---- hash levels 3..7, single launch, bf16x2 plane output ----
__global__ __launch_bounds__(256) void hash_levels(
    const float* __restrict__ xs,
    const uint32_t* __restrict__ bt,
    uint32_t* __restrict__ planes)     // 5 x kBatch u32
{
    const uint32_t lvl = blockIdx.x >> 13;               // 0..4 -> level 3..7
    const int p = (int)(blockIdx.x & 8191u) * 256 + threadIdx.x;
    const uint32_t* __restrict__ tl = bt + (size_t)(lvl + 3u) * kHash;

    const float px = xs[3 * p + 0];
    const float py = xs[3 * p + 1];
    const float pz = xs[3 * p + 2];

    const float scale = (float)((128u << lvl) - 1u);
    const float fx = px * scale + 0.5f;
    const float fy = py * scale + 0.5f;
    const float fz = pz * scale + 0.5f;
    const float flx = floorf(fx), fly = floorf(fy), flz = floorf(fz);
    const float rx = fx - flx, ry = fy - fly, rz = fz - flz;
    const uint32_t bx = (uint32_t)flx;
    const uint32_t by = (uint32_t)fly;
    const uint32_t bz = (uint32_t)flz;

    const uint32_t hy0 = by * 2654435761u, hy1 = (by + 1u) * 2654435761u;
    const uint32_t hz0 = bz * 805459861u,  hz1 = (bz + 1u) * 805459861u;
    uint32_t hyz[4] = {hy0 ^ hz0, hy1 ^ hz0, hy0 ^ hz1, hy1 ^ hz1};

    uint32_t i0[4];
#pragma unroll
    for (int k = 0; k < 4; ++k) i0[k] = (bx ^ hyz[k]) & (kHash - 1u);

    u32x2 v[4];
#pragma unroll
    for (int k = 0; k < 4; ++k)
        v[k] = *reinterpret_cast<const u32x2*>(tl + (i0[k] & ~1u));

    const bool bxodd = (bx & 1u) != 0u;
    uint32_t e0[4], e1[4];
    if (bxodd) {
#pragma unroll
        for (int k = 0; k < 4; ++k)
            e1[k] = tl[((bx + 1u) ^ hyz[k]) & (kHash - 1u)];
    }
#pragma unroll
    for (int k = 0; k < 4; ++k) {
        const bool lo = (i0[k] & 1u) != 0u;
        e0[k] = lo ? v[k].y : v[k].x;
        if (!bxodd) e1[k] = lo ? v[k].x : v[k].y;   // idx^1 partner
    }

    const float wx0 = 1.0f - rx, wx1 = rx;
    const float wyz[4] = {(1.0f - ry) * (1.0f - rz), ry * (1.0f - rz),
                          (1.0f - ry) * rz,          ry * rz};
    float a0 = 0.0f, a1 = 0.0f;
#pragma unroll
    for (int k = 0; k < 4; ++k) {
        const float w0 = wx0 * wyz[k], w1 = wx1 * wyz[k];
        a0 = fmaf(bf_lo(e0[k]), w0, fmaf(bf_lo(e1[k]), w1, a0));
        a1 = fmaf(bf_hi(e0[k]), w0, fmaf(bf_hi(e1[k]), w1, a1));
    }

    planes[(size_t)lvl * kBatch + p] = bf16rn(a0) | (bf16rn(a1) << 16);
}

// ---- merge: persistent blocks; dense 0-1 (LDS once), 2 (L2 paired),
//      5 planes -> full 64 B row NT writes ----
__global__ __launch_bounds__(1024) void merge_dense(
    const float* __restrict__ xs,
    const uint32_t* __restrict__ bt,
    const uint32_t* __restrict__ planes,
    float* __restrict__ out)
{
    __shared__ uint32_t sh[kL0Ents + kL1Ents];  // 152.8 KB

    for (uint32_t i = threadIdx.x; i < kL0Ents; i += 1024u)
        sh[i] = bt[i];
    for (uint32_t i = threadIdx.x; i < kL1Ents; i += 1024u)
        sh[kL0Ents + i] = bt[kHash + i];
    __syncthreads();

    constexpr int kStride = 256 * 1024;          // pts per sweep
    constexpr int kIters  = kBatch / kStride;    // 8

#pragma unroll 2
    for (int it = 0; it < kIters; ++it) {
        const int p = it * kStride + (int)blockIdx.x * 1024 + (int)threadIdx.x;

        const float px = xs[3 * p + 0];
        const float py = xs[3 * p + 1];
        const float pz = xs[3 * p + 2];

        float row[16];

        // levels 0,1 from LDS
#pragma unroll
        for (int l = 0; l < 2; ++l) {
            const uint32_t res    = (l == 0) ? 16u : 32u;
            const uint32_t shbase = (l == 0) ? 0u  : kL0Ents;
            const float scale = (float)(res - 1u);
            const float fx = px * scale + 0.5f;
            const float fy = py * scale + 0.5f;
            const float fz = pz * scale + 0.5f;
            const float flx = floorf(fx), fly = floorf(fy), flz = floorf(fz);
            const float rx = fx - flx, ry = fy - fly, rz = fz - flz;
            const uint32_t bx = (uint32_t)flx;
            const uint32_t by = (uint32_t)fly;
            const uint32_t bz = (uint32_t)flz;

            const float wx0 = 1.0f - rx, wx1 = rx;
            const float wyz[4] = {(1.0f - ry) * (1.0f - rz), ry * (1.0f - rz),
                                  (1.0f - ry) * rz,          ry * rz};
            float a0 = 0.0f, a1 = 0.0f;
#pragma unroll
            for (int k = 0; k < 4; ++k) {
                const uint32_t oy = k & 1u, oz = (k >> 1) & 1u;
                const uint32_t i0 = bx + (by + oy) * res + (bz + oz) * res * res;
                const uint32_t eA = sh[shbase + i0];
                const uint32_t eB = sh[shbase + i0 + 1u];
                const float w0 = wx0 * wyz[k], w1 = wx1 * wyz[k];
                a0 = fmaf(bf_lo(eA), w0, fmaf(bf_lo(eB), w1, a0));
                a1 = fmaf(bf_hi(eA), w0, fmaf(bf_hi(eB), w1, a1));
            }
            row[2 * l + 0] = a0;
            row[2 * l + 1] = a1;
        }

        // level 2 (res 64) from global, x-paired
        {
            const uint32_t res = 64u;
            const uint32_t* __restrict__ tl = bt + (size_t)2 * kHash;
            const float scale = (float)(res - 1u);
            const float fx = px * scale + 0.5f;
            const float fy = py * scale + 0.5f;
            const float fz = pz * scale + 0.5f;
            const float flx = floorf(fx), fly = floorf(fy), flz = floorf(fz);
            const float rx = fx - flx, ry = fy - fly, rz = fz - flz;
            const uint32_t bx = (uint32_t)flx;
            const uint32_t by = (uint32_t)fly;
            const uint32_t bz = (uint32_t)flz;

            uint32_t i0[4];
#pragma unroll
            for (int k = 0; k < 4; ++k) {
                const uint32_t oy = k & 1u, oz = (k >> 1) & 1u;
                i0[k] = bx + (by + oy) * res + (bz + oz) * res * res;
            }
            u32x2 v[4];
#pragma unroll
            for (int k = 0; k < 4; ++k)
                v[k] = *reinterpret_cast<const u32x2*>(tl + (i0[k] & ~1u));

            const bool bxodd = (bx & 1u) != 0u;
            uint32_t e0[4], e1[4];
            if (bxodd) {
#pragma unroll
                for (int k = 0; k < 4; ++k) e1[k] = tl[i0[k] + 1u];
            }
#pragma unroll
            for (int k = 0; k < 4; ++k) {
                e0[k] = bxodd ? v[k].y : v[k].x;
                if (!bxodd) e1[k] = v[k].y;
            }

            const float wx0 = 1.0f - rx, wx1 = rx;
            const float wyz[4] = {(1.0f - ry) * (1.0f - rz), ry * (1.0f - rz),
                                  (1.0f - ry) * rz,          ry * rz};
            float a0 = 0.0f, a1 = 0.0f;
#pragma unroll
            for (int k = 0; k < 4; ++k) {
                const float w0 = wx0 * wyz[k], w1 = wx1 * wyz[k];
                a0 = fmaf(bf_lo(e0[k]), w0, fmaf(bf_lo(e1[k]), w1, a0));
                a1 = fmaf(bf_hi(e0[k]), w0, fmaf(bf_hi(e1[k]), w1, a1));
            }
            row[4] = a0;
            row[5] = a1;
        }

        // hash levels from planes
#pragma unroll
        for (int l = 0; l < 5; ++l) {
            const uint32_t w = planes[(size_t)l * kBatch + p];
            row[6 + 2 * l + 0] = bf_lo(w);
            row[6 + 2 * l + 1] = bf_hi(w);
        }

        f32x4* op = reinterpret_cast<f32x4*>(out + (size_t)p * 16u);
#pragma unroll
        for (int i = 0; i < 4; ++i) {
            f32x4 q;
            q.x = row[4 * i + 0]; q.y = row[4 * i + 1];
            q.z = row[4 * i + 2]; q.w = row[4 * i + 3];
            __builtin_nontemporal_store(q, op + i);
        }
    }
}

// ---- fallback (small ws): monolithic f32 kernel (R1) ----
__global__ __launch_bounds__(256) void tcnn_grid_fallback(
    const float* __restrict__ xs, const float* __restrict__ table,
    float* __restrict__ out)
{
    const int p = blockIdx.x * 256 + threadIdx.x;
    const float px = xs[3 * p + 0], py = xs[3 * p + 1], pz = xs[3 * p + 2];
    float o[16];
#pragma unroll
    for (int l = 0; l < 8; ++l) {
        const uint32_t res = 16u << l;
        const bool dense = (l < 3);
        const float scale = (float)(res - 1u);
        const float fx = px * scale + 0.5f, fy = py * scale + 0.5f,
                    fz = pz * scale + 0.5f;
        const float flx = floorf(fx), fly = floorf(fy), flz = floorf(fz);
        const float rx = fx - flx, ry = fy - fly, rz = fz - flz;
        const uint32_t bx = (uint32_t)flx, by = (uint32_t)fly,
                       bz = (uint32_t)flz;
        const float* tl = table + (size_t)l * kHash * 2u;
        float a0 = 0.0f, a1 = 0.0f;
#pragma unroll
        for (int c = 0; c < 8; ++c) {
            const uint32_t ox = c & 1u, oy = (c >> 1) & 1u, oz = (c >> 2) & 1u;
            uint32_t idx;
            if (dense)
                idx = (bx + ox) + (by + oy) * res + (bz + oz) * res * res;
            else
                idx = ((bx + ox) ^ ((by + oy) * 2654435761u) ^
                       ((bz + oz) * 805459861u)) & (kHash - 1u);
            const float2 f = *reinterpret_cast<const float2*>(tl + 2u * (size_t)idx);
            const float w = (ox ? rx : 1.0f - rx) * (oy ? ry : 1.0f - ry) *
                            (oz ? rz : 1.0f - rz);
            a0 = fmaf(f.x, w, a0);
            a1 = fmaf(f.y, w, a1);
        }
        o[2 * l] = a0; o[2 * l + 1] = a1;
    }
    float4* op = reinterpret_cast<float4*>(out + (size_t)p * 16u);
#pragma unroll
    for (int i = 0; i < 4; ++i)
        op[i] = make_float4(o[4 * i], o[4 * i + 1], o[4 * i + 2], o[4 * i + 3]);
}

extern "C" void kernel_launch(void* const* d_in, const int* in_sizes, int n_in,
                              void* d_out, int out_size, void* d_ws,
                              size_t ws_size, hipStream_t stream) {
    const float* xs    = (const float*)d_in[0];
    const float* table = (const float*)d_in[1];
    float*       out   = (float*)d_out;

    if (ws_size < kWsNeed) {
        hipLaunchKernelGGL(tcnn_grid_fallback, dim3(kBatch / 256), dim3(256),
                           0, stream, xs, table, out);
        return;
    }

    uint32_t* bt     = (uint32_t*)d_ws;                 // 16 MB bf16x2 tables
    uint32_t* planes = bt + (size_t)8 * kHash;          // 5 x 8 MB bf16x2

    hipLaunchKernelGGL(convert_tables, dim3(kBatch / 256), dim3(256), 0,
                       stream, table, bt);

    hipLaunchKernelGGL(hash_levels, dim3(5 * (kBatch / 256)), dim3(256), 0,
                       stream, xs, bt, planes);

    hipLaunchKernelGGL(merge_dense, dim3(256), dim3(1024), 0,
                       stream, xs, bt, planes, out);
}

// Round 9
// 363.009 us; speedup vs baseline: 1.1217x; 1.0829x over previous
//
#include <hip/hip_runtime.h>
#include <cstdint>

// TCNN hash-grid fwd, R9 = R6 re-land (best known: 363 us) + plane-load hoist
// in merge. R7 (2pt/thread ILP) and R8 (persistent merge) both falsified.
//  - bf16-packed tables in ws (convert pre-pass)
//  - hash levels 3-7 in ONE launch (slice = blockIdx>>13), writing compact
//    bf16x2 planes (ws)
//  - merge kernel (2048 blocks x 1024 thr): dense 0-1 from LDS, level 2 from
//    L2 (x-paired), 5 plane reads (hoisted), full 64 B row NT writes.

constexpr int      kBatch  = 2097152;
constexpr uint32_t kHash   = 1u << 19;
constexpr size_t   kWsNeed = (size_t)(16 + 40) * 1024 * 1024;

typedef float    f32x2 __attribute__((ext_vector_type(2)));
typedef float    f32x4 __attribute__((ext_vector_type(4)));
typedef uint32_t u32x2 __attribute__((ext_vector_type(2)));

constexpr uint32_t kL0Ents = 16u + 16u * 16u + 16u * 16u * 16u + 1u;   // 4369
constexpr uint32_t kL1Ents = 32u + 32u * 32u + 32u * 32u * 32u + 1u;   // 33825

__device__ __forceinline__ uint32_t bf16rn(float f) {
    uint32_t u = __float_as_uint(f);
    return (u + 0x7FFFu + ((u >> 16) & 1u)) >> 16;
}
__device__ __forceinline__ float bf_lo(uint32_t w) {
    return __uint_as_float(w << 16);
}
__device__ __forceinline__ float bf_hi(uint32_t w) {
    return __uint_as_float(w & 0xFFFF0000u);
}

// ---- pack f32 table [8,2^19,2] -> bf16x2 words [8,2^19] ----
__global__ __launch_bounds__(256) void convert_tables(
    const float* __restrict__ table, uint32_t* __restrict__ bt)
{
    const size_t i = (size_t)blockIdx.x * 256 + threadIdx.x;
    const f32x4 v = __builtin_nontemporal_load(
        reinterpret_cast<const f32x4*>(table) + i);
    u32x2 o;
    o.x = bf16rn(v.x) | (bf16rn(v.y) << 16);
    o.y = bf16rn(v.z) | (bf16rn(v.w) << 16);
    __builtin_nontemporal_store(o, reinterpret_cast<u32x2*>(bt) + i);
}

// ---- hash levels 3..7, single launch, bf16x2 plane output ----
__global__ __launch_bounds__(256) void hash_levels(
    const float* __restrict__ xs,
    const uint32_t* __restrict__ bt,
    uint32_t* __restrict__ planes)     // 5 x kBatch u32
{
    const uint32_t lvl = blockIdx.x >> 13;               // 0..4 -> level 3..7
    const int p = (int)(blockIdx.x & 8191u) * 256 + threadIdx.x;
    const uint32_t* __restrict__ tl = bt + (size_t)(lvl + 3u) * kHash;

    const float px = xs[3 * p + 0];
    const float py = xs[3 * p + 1];
    const float pz = xs[3 * p + 2];

    const float scale = (float)((128u << lvl) - 1u);
    const float fx = px * scale + 0.5f;
    const float fy = py * scale + 0.5f;
    const float fz = pz * scale + 0.5f;
    const float flx = floorf(fx), fly = floorf(fy), flz = floorf(fz);
    const float rx = fx - flx, ry = fy - fly, rz = fz - flz;
    const uint32_t bx = (uint32_t)flx;
    const uint32_t by = (uint32_t)fly;
    const uint32_t bz = (uint32_t)flz;

    const uint32_t hy0 = by * 2654435761u, hy1 = (by + 1u) * 2654435761u;
    const uint32_t hz0 = bz * 805459861u,  hz1 = (bz + 1u) * 805459861u;
    uint32_t hyz[4] = {hy0 ^ hz0, hy1 ^ hz0, hy0 ^ hz1, hy1 ^ hz1};

    uint32_t i0[4];
#pragma unroll
    for (int k = 0; k < 4; ++k) i0[k] = (bx ^ hyz[k]) & (kHash - 1u);

    u32x2 v[4];
#pragma unroll
    for (int k = 0; k < 4; ++k)
        v[k] = *reinterpret_cast<const u32x2*>(tl + (i0[k] & ~1u));

    const bool bxodd = (bx & 1u) != 0u;
    uint32_t e0[4], e1[4];
    if (bxodd) {
#pragma unroll
        for (int k = 0; k < 4; ++k)
            e1[k] = tl[((bx + 1u) ^ hyz[k]) & (kHash - 1u)];
    }
#pragma unroll
    for (int k = 0; k < 4; ++k) {
        const bool lo = (i0[k] & 1u) != 0u;
        e0[k] = lo ? v[k].y : v[k].x;
        if (!bxodd) e1[k] = lo ? v[k].x : v[k].y;   // idx^1 partner
    }

    const float wx0 = 1.0f - rx, wx1 = rx;
    const float wyz[4] = {(1.0f - ry) * (1.0f - rz), ry * (1.0f - rz),
                          (1.0f - ry) * rz,          ry * rz};
    float a0 = 0.0f, a1 = 0.0f;
#pragma unroll
    for (int k = 0; k < 4; ++k) {
        const float w0 = wx0 * wyz[k], w1 = wx1 * wyz[k];
        a0 = fmaf(bf_lo(e0[k]), w0, fmaf(bf_lo(e1[k]), w1, a0));
        a1 = fmaf(bf_hi(e0[k]), w0, fmaf(bf_hi(e1[k]), w1, a1));
    }

    planes[(size_t)lvl * kBatch + p] = bf16rn(a0) | (bf16rn(a1) << 16);
}

// ---- merge: dense 0-1 (LDS), 2 (global paired), + 5 planes -> full rows ----
__global__ __launch_bounds__(1024) void merge_dense(
    const float* __restrict__ xs,
    const uint32_t* __restrict__ bt,
    const uint32_t* __restrict__ planes,
    float* __restrict__ out)
{
    __shared__ uint32_t sh[kL0Ents + kL1Ents];  // 152.8 KB

    for (uint32_t i = threadIdx.x; i < kL0Ents; i += 1024u)
        sh[i] = bt[i];
    for (uint32_t i = threadIdx.x; i < kL1Ents; i += 1024u)
        sh[kL0Ents + i] = bt[kHash + i];
    __syncthreads();

    const int p = blockIdx.x * 1024 + threadIdx.x;
    const float px = xs[3 * p + 0];
    const float py = xs[3 * p + 1];
    const float pz = xs[3 * p + 2];

    // hoist the coalesced plane loads so they are in flight under the
    // level-2 gather latency
    uint32_t pw[5];
#pragma unroll
    for (int l = 0; l < 5; ++l)
        pw[l] = planes[(size_t)l * kBatch + p];

    float row[16];

    // levels 0,1 from LDS
#pragma unroll
    for (int l = 0; l < 2; ++l) {
        const uint32_t res    = (l == 0) ? 16u : 32u;
        const uint32_t shbase = (l == 0) ? 0u  : kL0Ents;
        const float scale = (float)(res - 1u);
        const float fx = px * scale + 0.5f;
        const float fy = py * scale + 0.5f;
        const float fz = pz * scale + 0.5f;
        const float flx = floorf(fx), fly = floorf(fy), flz = floorf(fz);
        const float rx = fx - flx, ry = fy - fly, rz = fz - flz;
        const uint32_t bx = (uint32_t)flx;
        const uint32_t by = (uint32_t)fly;
        const uint32_t bz = (uint32_t)flz;

        const float wx0 = 1.0f - rx, wx1 = rx;
        const float wyz[4] = {(1.0f - ry) * (1.0f - rz), ry * (1.0f - rz),
                              (1.0f - ry) * rz,          ry * rz};
        float a0 = 0.0f, a1 = 0.0f;
#pragma unroll
        for (int k = 0; k < 4; ++k) {
            const uint32_t oy = k & 1u, oz = (k >> 1) & 1u;
            const uint32_t i0 = bx + (by + oy) * res + (bz + oz) * res * res;
            const uint32_t eA = sh[shbase + i0];
            const uint32_t eB = sh[shbase + i0 + 1u];
            const float w0 = wx0 * wyz[k], w1 = wx1 * wyz[k];
            a0 = fmaf(bf_lo(eA), w0, fmaf(bf_lo(eB), w1, a0));
            a1 = fmaf(bf_hi(eA), w0, fmaf(bf_hi(eB), w1, a1));
        }
        row[2 * l + 0] = a0;
        row[2 * l + 1] = a1;
    }

    // level 2 (res 64) from global, x-paired
    {
        const uint32_t res = 64u;
        const uint32_t* __restrict__ tl = bt + (size_t)2 * kHash;
        const float scale = (float)(res - 1u);
        const float fx = px * scale + 0.5f;
        const float fy = py * scale + 0.5f;
        const float fz = pz * scale + 0.5f;
        const float flx = floorf(fx), fly = floorf(fy), flz = floorf(fz);
        const float rx = fx - flx, ry = fy - fly, rz = fz - flz;
        const uint32_t bx = (uint32_t)flx;
        const uint32_t by = (uint32_t)fly;
        const uint32_t bz = (uint32_t)flz;

        uint32_t i0[4];
#pragma unroll
        for (int k = 0; k < 4; ++k) {
            const uint32_t oy = k & 1u, oz = (k >> 1) & 1u;
            i0[k] = bx + (by + oy) * res + (bz + oz) * res * res;
        }
        u32x2 v[4];
#pragma unroll
        for (int k = 0; k < 4; ++k)
            v[k] = *reinterpret_cast<const u32x2*>(tl + (i0[k] & ~1u));

        const bool bxodd = (bx & 1u) != 0u;
        uint32_t e0[4], e1[4];
        if (bxodd) {
#pragma unroll
            for (int k = 0; k < 4; ++k) e1[k] = tl[i0[k] + 1u];
        }
#pragma unroll
        for (int k = 0; k < 4; ++k) {
            e0[k] = bxodd ? v[k].y : v[k].x;
            if (!bxodd) e1[k] = v[k].y;
        }

        const float wx0 = 1.0f - rx, wx1 = rx;
        const float wyz[4] = {(1.0f - ry) * (1.0f - rz), ry * (1.0f - rz),
                              (1.0f - ry) * rz,          ry * rz};
        float a0 = 0.0f, a1 = 0.0f;
#pragma unroll
        for (int k = 0; k < 4; ++k) {
            const float w0 = wx0 * wyz[k], w1 = wx1 * wyz[k];
            a0 = fmaf(bf_lo(e0[k]), w0, fmaf(bf_lo(e1[k]), w1, a0));
            a1 = fmaf(bf_hi(e0[k]), w0, fmaf(bf_hi(e1[k]), w1, a1));
        }
        row[4] = a0;
        row[5] = a1;
    }

    // hash levels from (already loaded) plane words
#pragma unroll
    for (int l = 0; l < 5; ++l) {
        row[6 + 2 * l + 0] = bf_lo(pw[l]);
        row[6 + 2 * l + 1] = bf_hi(pw[l]);
    }

    f32x4* op = reinterpret_cast<f32x4*>(out + (size_t)p * 16u);
#pragma unroll
    for (int i = 0; i < 4; ++i) {
        f32x4 q;
        q.x = row[4 * i + 0]; q.y = row[4 * i + 1];
        q.z = row[4 * i + 2]; q.w = row[4 * i + 3];
        __builtin_nontemporal_store(q, op + i);
    }
}

// ---- fallback (small ws): monolithic f32 kernel (R1) ----
__global__ __launch_bounds__(256) void tcnn_grid_fallback(
    const float* __restrict__ xs, const float* __restrict__ table,
    float* __restrict__ out)
{
    const int p = blockIdx.x * 256 + threadIdx.x;
    const float px = xs[3 * p + 0], py = xs[3 * p + 1], pz = xs[3 * p + 2];
    float o[16];
#pragma unroll
    for (int l = 0; l < 8; ++l) {
        const uint32_t res = 16u << l;
        const bool dense = (l < 3);
        const float scale = (float)(res - 1u);
        const float fx = px * scale + 0.5f, fy = py * scale + 0.5f,
                    fz = pz * scale + 0.5f;
        const float flx = floorf(fx), fly = floorf(fy), flz = floorf(fz);
        const float rx = fx - flx, ry = fy - fly, rz = fz - flz;
        const uint32_t bx = (uint32_t)flx, by = (uint32_t)fly,
                       bz = (uint32_t)flz;
        const float* tl = table + (size_t)l * kHash * 2u;
        float a0 = 0.0f, a1 = 0.0f;
#pragma unroll
        for (int c = 0; c < 8; ++c) {
            const uint32_t ox = c & 1u, oy = (c >> 1) & 1u, oz = (c >> 2) & 1u;
            uint32_t idx;
            if (dense)
                idx = (bx + ox) + (by + oy) * res + (bz + oz) * res * res;
            else
                idx = ((bx + ox) ^ ((by + oy) * 2654435761u) ^
                       ((bz + oz) * 805459861u)) & (kHash - 1u);
            const float2 f = *reinterpret_cast<const float2*>(tl + 2u * (size_t)idx);
            const float w = (ox ? rx : 1.0f - rx) * (oy ? ry : 1.0f - ry) *
                            (oz ? rz : 1.0f - rz);
            a0 = fmaf(f.x, w, a0);
            a1 = fmaf(f.y, w, a1);
        }
        o[2 * l] = a0; o[2 * l + 1] = a1;
    }
    float4* op = reinterpret_cast<float4*>(out + (size_t)p * 16u);
#pragma unroll
    for (int i = 0; i < 4; ++i)
        op[i] = make_float4(o[4 * i], o[4 * i + 1], o[4 * i + 2], o[4 * i + 3]);
}

extern "C" void kernel_launch(void* const* d_in, const int* in_sizes, int n_in,
                              void* d_out, int out_size, void* d_ws,
                              size_t ws_size, hipStream_t stream) {
    const float* xs    = (const float*)d_in[0];
    const float* table = (const float*)d_in[1];
    float*       out   = (float*)d_out;

    if (ws_size < kWsNeed) {
        hipLaunchKernelGGL(tcnn_grid_fallback, dim3(kBatch / 256), dim3(256),
                           0, stream, xs, table, out);
        return;
    }

    uint32_t* bt     = (uint32_t*)d_ws;                 // 16 MB bf16x2 tables
    uint32_t* planes = bt + (size_t)8 * kHash;          // 5 x 8 MB bf16x2

    hipLaunchKernelGGL(convert_tables, dim3(kBatch / 256), dim3(256), 0,
                       stream, table, bt);

    hipLaunchKernelGGL(hash_levels, dim3(5 * (kBatch / 256)), dim3(256), 0,
                       stream, xs, bt, planes);

    hipLaunchKernelGGL(merge_dense, dim3(kBatch / 1024), dim3(1024), 0,
                       stream, xs, bt, planes, out);
}